// Round 1
// baseline (137.777 us; speedup 1.0000x reference)
//
#include <hip/hip_runtime.h>
#include <hip/hip_bf16.h>
#include <cstdint>
#include <cstddef>

#define NN 8192
#define IN_F 256
#define HID_F 128
#define OUT_F 64

typedef __attribute__((ext_vector_type(8))) short short8v;
typedef __attribute__((ext_vector_type(4))) float f32x4;
typedef __attribute__((ext_vector_type(4))) unsigned short ushort4v;

// bf16 round-to-nearest-even split helpers (inputs finite)
static __device__ __forceinline__ unsigned short f2bf(float x) {
    unsigned int u = __float_as_uint(x);
    unsigned int r = (u + 0x7fffu + ((u >> 16) & 1u)) >> 16;
    return (unsigned short)r;
}
static __device__ __forceinline__ float bf2f(unsigned short u) {
    return __uint_as_float(((unsigned int)u) << 16);
}

// ---------------- row_ptr from sorted edge_src ----------------
__global__ void k_rowptr(const int* __restrict__ src, int* __restrict__ rp, int E, int N) {
    int i = blockIdx.x * blockDim.x + threadIdx.x;
    if (i >= E) return;
    int s = src[i];
    int p = (i == 0) ? -1 : src[i - 1];
    for (int n = p + 1; n <= s; ++n) rp[n] = i;
    if (i == E - 1) {
        for (int n = s + 1; n <= N; ++n) rp[n] = E;
    }
}

__global__ void k_norm(const int* __restrict__ rp, float* __restrict__ norm, int N) {
    int n = blockIdx.x * blockDim.x + threadIdx.x;
    if (n >= N) return;
    int d = rp[n + 1] - rp[n];
    float df = (float)(d < 1 ? 1 : d);
    norm[n] = rsqrtf(df);
}

// ---------------- convert h*norm -> bf16 hi/lo ----------------
__global__ void k_conv_h(const float* __restrict__ h, const float* __restrict__ norm,
                         unsigned short* __restrict__ hi, unsigned short* __restrict__ lo,
                         int total4) {
    int i = blockIdx.x * blockDim.x + threadIdx.x;
    if (i >= total4) return;
    int n = i / (IN_F / 4);
    float nv = norm[n];
    float4 v = reinterpret_cast<const float4*>(h)[i];
    ushort4v h4, l4;
    float x;
    x = v.x * nv; h4.x = f2bf(x); l4.x = f2bf(x - bf2f(h4.x));
    x = v.y * nv; h4.y = f2bf(x); l4.y = f2bf(x - bf2f(h4.y));
    x = v.z * nv; h4.z = f2bf(x); l4.z = f2bf(x - bf2f(h4.z));
    x = v.w * nv; h4.w = f2bf(x); l4.w = f2bf(x - bf2f(h4.w));
    reinterpret_cast<ushort4v*>(hi)[i] = h4;
    reinterpret_cast<ushort4v*>(lo)[i] = l4;
}

// ---------------- convert W0 and [Wmu;Wls] -> bf16 hi/lo ----------------
__global__ void k_conv_w(const float* __restrict__ W0, const float* __restrict__ Wmu,
                         const float* __restrict__ Wls,
                         unsigned short* __restrict__ W0h, unsigned short* __restrict__ W0l,
                         unsigned short* __restrict__ Wch, unsigned short* __restrict__ Wcl) {
    int i = blockIdx.x * blockDim.x + threadIdx.x;
    const int n0 = HID_F * IN_F;          // 32768
    const int n1 = 2 * OUT_F * HID_F;     // 16384 (concat [Wmu;Wls] as [128][128])
    if (i < n0) {
        float x = W0[i];
        unsigned short hh = f2bf(x);
        W0h[i] = hh; W0l[i] = f2bf(x - bf2f(hh));
    } else if (i < n0 + n1) {
        int j = i - n0;
        int r = j / HID_F, c = j % HID_F;
        float x = (r < OUT_F) ? Wmu[r * HID_F + c] : Wls[(r - OUT_F) * HID_F + c];
        unsigned short hh = f2bf(x);
        Wch[j] = hh; Wcl[j] = f2bf(x - bf2f(hh));
    }
}

// ---------------- generic C = A * B^T, split-bf16, fp32 acc ----------------
// A: [M][K] row-major as bf16 hi/lo, B: [N][K] row-major as bf16 hi/lo.
// 4 waves arranged 2x2; wave tile = (16*MT) x (16*NT); block tile = (32*MT) x (32*NT).
template <int K, int MT, int NT>
__global__ __launch_bounds__(256) void k_gemm_bt(
    const unsigned short* __restrict__ Ahi, const unsigned short* __restrict__ Alo,
    const unsigned short* __restrict__ Bhi, const unsigned short* __restrict__ Blo,
    float* __restrict__ C, int ldc) {
    const int lane = threadIdx.x & 63;
    const int wid = threadIdx.x >> 6;
    const int wr = wid >> 1, wc = wid & 1;
    const long i0 = (long)blockIdx.x * (32 * MT) + wr * (16 * MT);
    const long j0 = (long)blockIdx.y * (32 * NT) + wc * (16 * NT);
    const int rl = lane & 15;
    const int kq = lane >> 4;

    f32x4 acc[MT][NT] = {};

    for (int kc = 0; kc < K; kc += 32) {
        const int kb = kc + kq * 8;
        short8v ah[MT], al[MT], bh[NT], bl[NT];
#pragma unroll
        for (int m = 0; m < MT; ++m) {
            size_t off = (size_t)(i0 + m * 16 + rl) * K + kb;
            ah[m] = *reinterpret_cast<const short8v*>(Ahi + off);
            al[m] = *reinterpret_cast<const short8v*>(Alo + off);
        }
#pragma unroll
        for (int n = 0; n < NT; ++n) {
            size_t off = (size_t)(j0 + n * 16 + rl) * K + kb;
            bh[n] = *reinterpret_cast<const short8v*>(Bhi + off);
            bl[n] = *reinterpret_cast<const short8v*>(Blo + off);
        }
#pragma unroll
        for (int m = 0; m < MT; ++m) {
#pragma unroll
            for (int n = 0; n < NT; ++n) {
                acc[m][n] = __builtin_amdgcn_mfma_f32_16x16x32_bf16(ah[m], bh[n], acc[m][n], 0, 0, 0);
                acc[m][n] = __builtin_amdgcn_mfma_f32_16x16x32_bf16(ah[m], bl[n], acc[m][n], 0, 0, 0);
                acc[m][n] = __builtin_amdgcn_mfma_f32_16x16x32_bf16(al[m], bh[n], acc[m][n], 0, 0, 0);
            }
        }
    }

    const int crow = (lane >> 4) * 4;  // + reg -> row within 16x16 tile
#pragma unroll
    for (int m = 0; m < MT; ++m) {
#pragma unroll
        for (int n = 0; n < NT; ++n) {
            size_t base = (size_t)(i0 + m * 16 + crow) * ldc + (size_t)(j0 + n * 16 + rl);
#pragma unroll
            for (int r = 0; r < 4; ++r)
                C[base + (size_t)r * ldc] = acc[m][n][r];
        }
    }
}

// ---------------- SpMM 1: h1p = relu(segsum(X1[dst]) * norm) * norm ----------------
__global__ __launch_bounds__(128) void k_spmm1(
    const float* __restrict__ X, const int* __restrict__ rp, const int* __restrict__ dst,
    const float* __restrict__ norm, float* __restrict__ h1p) {
    int n = blockIdx.x;
    int t = threadIdx.x;
    int e0 = rp[n], e1 = rp[n + 1];
    float acc = 0.f;
    int e = e0;
    for (; e + 4 <= e1; e += 4) {
        int d0 = dst[e] * HID_F, d1 = dst[e + 1] * HID_F;
        int d2 = dst[e + 2] * HID_F, d3 = dst[e + 3] * HID_F;
        acc += X[d0 + t];
        acc += X[d1 + t];
        acc += X[d2 + t];
        acc += X[d3 + t];
    }
    for (; e < e1; ++e) acc += X[dst[e] * HID_F + t];
    float nv = norm[n];
    float v = acc * nv;
    v = v > 0.f ? v : 0.f;
    h1p[n * HID_F + t] = v * nv;
}

// ---------------- SpMM 2: agg = segsum(h1p[dst]) -> bf16 hi/lo ----------------
__global__ __launch_bounds__(128) void k_spmm2(
    const float* __restrict__ X, const int* __restrict__ rp, const int* __restrict__ dst,
    unsigned short* __restrict__ hi, unsigned short* __restrict__ lo) {
    int n = blockIdx.x;
    int t = threadIdx.x;
    int e0 = rp[n], e1 = rp[n + 1];
    float acc = 0.f;
    int e = e0;
    for (; e + 4 <= e1; e += 4) {
        int d0 = dst[e] * HID_F, d1 = dst[e + 1] * HID_F;
        int d2 = dst[e + 2] * HID_F, d3 = dst[e + 3] * HID_F;
        acc += X[d0 + t];
        acc += X[d1 + t];
        acc += X[d2 + t];
        acc += X[d3 + t];
    }
    for (; e < e1; ++e) acc += X[dst[e] * HID_F + t];
    unsigned short hh = f2bf(acc);
    hi[n * HID_F + t] = hh;
    lo[n * HID_F + t] = f2bf(acc - bf2f(hh));
}

// ---------------- z = P[:, :64]*norm + exp(P[:, 64:]*norm)*eps -> bf16 hi/lo ----------------
__global__ void k_z(const float* __restrict__ P, const float* __restrict__ norm,
                    const float* __restrict__ eps,
                    unsigned short* __restrict__ zh, unsigned short* __restrict__ zl) {
    int i = blockIdx.x * blockDim.x + threadIdx.x;
    if (i >= NN * OUT_F) return;
    int n = i >> 6, f = i & 63;
    float nv = norm[n];
    float mu = P[n * HID_F + f] * nv;
    float ls = P[n * HID_F + 64 + f] * nv;
    float z = mu + expf(ls) * eps[i];
    unsigned short hh = f2bf(z);
    zh[i] = hh;
    zl[i] = f2bf(z - bf2f(hh));
}

extern "C" void kernel_launch(void* const* d_in, const int* in_sizes, int n_in,
                              void* d_out, int out_size, void* d_ws, size_t ws_size,
                              hipStream_t stream) {
    const float* h   = (const float*)d_in[0];
    const float* W0  = (const float*)d_in[1];
    const float* Wmu = (const float*)d_in[2];
    const float* Wls = (const float*)d_in[3];
    const float* eps = (const float*)d_in[4];
    const int* esrc  = (const int*)d_in[5];
    const int* edst  = (const int*)d_in[6];
    const int E = in_sizes[5];
    const int N = NN;

    char* w = (char*)d_ws;
    auto alloc = [&](size_t bytes) {
        char* p = w;
        w += (bytes + 511) & ~(size_t)511;
        return p;
    };
    int* rp             = (int*)alloc((N + 1) * sizeof(int));
    float* norm         = (float*)alloc(N * sizeof(float));
    unsigned short* Hh  = (unsigned short*)alloc((size_t)N * IN_F * 2);
    unsigned short* Hl  = (unsigned short*)alloc((size_t)N * IN_F * 2);
    unsigned short* W0h = (unsigned short*)alloc(HID_F * IN_F * 2);
    unsigned short* W0l = (unsigned short*)alloc(HID_F * IN_F * 2);
    unsigned short* Wch = (unsigned short*)alloc(2 * OUT_F * HID_F * 2);
    unsigned short* Wcl = (unsigned short*)alloc(2 * OUT_F * HID_F * 2);
    float* X1           = (float*)alloc((size_t)N * HID_F * sizeof(float));
    float* h1p          = (float*)alloc((size_t)N * HID_F * sizeof(float));
    unsigned short* Agh = (unsigned short*)alloc((size_t)N * HID_F * 2);
    unsigned short* Agl = (unsigned short*)alloc((size_t)N * HID_F * 2);
    float* P            = (float*)alloc((size_t)N * HID_F * sizeof(float));
    unsigned short* Zh  = (unsigned short*)alloc((size_t)N * OUT_F * 2);
    unsigned short* Zl  = (unsigned short*)alloc((size_t)N * OUT_F * 2);

    k_rowptr<<<(E + 255) / 256, 256, 0, stream>>>(esrc, rp, E, N);
    k_norm<<<(N + 255) / 256, 256, 0, stream>>>(rp, norm, N);
    k_conv_h<<<((N * IN_F / 4) + 255) / 256, 256, 0, stream>>>(h, norm, Hh, Hl, N * IN_F / 4);
    k_conv_w<<<(HID_F * IN_F + 2 * OUT_F * HID_F + 255) / 256, 256, 0, stream>>>(
        W0, Wmu, Wls, W0h, W0l, Wch, Wcl);

    // X1 = (h*norm) @ W0^T   [8192][128]
    k_gemm_bt<IN_F, 2, 2><<<dim3(N / 64, HID_F / 64), 256, 0, stream>>>(
        Hh, Hl, W0h, W0l, X1, HID_F);

    k_spmm1<<<N, 128, 0, stream>>>(X1, rp, edst, norm, h1p);
    k_spmm2<<<N, 128, 0, stream>>>(h1p, rp, edst, Agh, Agl);

    // P = agg @ [Wmu;Wls]^T  [8192][128]
    k_gemm_bt<HID_F, 2, 2><<<dim3(N / 64, HID_F / 64), 256, 0, stream>>>(
        Agh, Agl, Wch, Wcl, P, HID_F);

    k_z<<<((N * OUT_F) + 255) / 256, 256, 0, stream>>>(P, norm, eps, Zh, Zl);

    // logits = z @ z^T  [8192][8192]
    k_gemm_bt<OUT_F, 4, 4><<<dim3(N / 128, N / 128), 256, 0, stream>>>(
        Zh, Zl, Zh, Zl, (float*)d_out, N);
}